// Round 1
// 951.085 us; speedup vs baseline: 1.1775x; 1.1775x over previous
//
#include <hip/hip_runtime.h>
#include <hip/hip_bf16.h>

// DecoderRNN, fp32 in / fp32 out (reference dtypes), bf16 MFMA compute.
// Attention branch is dead code (softmax over a length-1 axis == 1 =>
// context == encoder_out; We/be/Wd/bd/Wf/bf never affect the output).
//   A) pre[t][g][b] = [emb(cap[b,t]), enc[b]] @ W_ih^T + b_ih + b_hh  (GEMM)
//      -> fp32, stored INSIDE d_out (dead space until out_kernel overwrites)
//   B) 64-step LSTM recurrence: 16 WGs x 128 gate rows, Whh fragments hoisted
//      to VGPRs, fence-free flag barrier (sc1 write-through h stores +
//      __syncthreads vmcnt drain provide release ordering). 240 spare WGs in
//      the same dispatch convert Wfc -> bf16 (overlapped with recurrence).
//   C) out = Hall @ W_fc^T + b_fc  (2048 x 30000 x 512), global_load_lds
//      staging of both bf16 operands; grid ordered so B-tile sharers are
//      dispatch-adjacent.

#define BATCH 32
#define TT 64
#define VV 30000
#define HH 512
#define G4 2048     // 4*H
#define KX 768      // EMB + E
#define RNN_WG 16   // recurrence workgroups (128 gate rows each)

typedef __bf16 bf16x8 __attribute__((ext_vector_type(8)));
typedef float f32x4 __attribute__((ext_vector_type(4)));
typedef __attribute__((address_space(1))) void gvoid;
typedef __attribute__((address_space(3))) void lvoid;

#define MFMA(a, b, c) __builtin_amdgcn_mfma_f32_16x16x32_bf16((a), (b), (c), 0, 0, 0)

__device__ __forceinline__ float sigf(float x) {
    return 1.0f / (1.0f + __expf(-x));   // safe: x=+-inf -> 0/1
}
__device__ __forceinline__ float tanh_fast(float x) {
    return 1.0f - 2.0f / (__expf(2.0f * x) + 1.0f);   // safe at +-inf
}
__device__ __forceinline__ bf16x8 cvt8(const float* __restrict__ p) {
    const f32x4 a = *(const f32x4*)p;
    const f32x4 b = *(const f32x4*)(p + 4);
    bf16x8 r;
    r[0] = (__bf16)a[0]; r[1] = (__bf16)a[1]; r[2] = (__bf16)a[2]; r[3] = (__bf16)a[3];
    r[4] = (__bf16)b[0]; r[5] = (__bf16)b[1]; r[6] = (__bf16)b[2]; r[7] = (__bf16)b[3];
    return r;
}

// ---------------------------------------------------------------------------
// Kernel A: pre[t][g][b] fp32, layout [T][2048][32]. 128x128xK768 per WG.
// M index m = t*32 + b.  (unchanged)
// ---------------------------------------------------------------------------
__global__ __launch_bounds__(256) void pre_kernel(
    const float* __restrict__ enc, const int* __restrict__ captions,
    const float* __restrict__ emb, const float* __restrict__ Wih,
    const float* __restrict__ bih, const float* __restrict__ bhh,
    float* __restrict__ pre) {
    __shared__ __bf16 aT[128 * 32];
    __shared__ __bf16 bT[128 * 32];
    __shared__ int capm[128];

    const int tid = threadIdx.x;
    const int nt = blockIdx.x;   // gate tile [0,16)
    const int mt = blockIdx.y;   // token tile [0,16)

    if (tid < 128) {
        int m = mt * 128 + tid;               // m = t*32 + b
        capm[tid] = captions[(m & 31) * TT + (m >> 5)];
    }

    const int lane = tid & 63, wv = tid >> 6;
    const int ln = lane & 15, quad = lane >> 4;
    const int wm = wv & 1, wn = wv >> 1;

    f32x4 acc[4][4] = {};
    __syncthreads();

    for (int kc = 0; kc < 24; ++kc) {
        const int k0 = kc * 32;
        for (int i = tid; i < 512; i += 256) {
            int r = i >> 2, seg = i & 3;
            const float* src;
            if (k0 < 512) {
                src = emb + (size_t)capm[r] * 512 + k0 + seg * 8;
            } else {
                int b = (mt * 128 + r) & 31;
                src = enc + b * 256 + (k0 - 512) + seg * 8;
            }
            *(bf16x8*)&aT[r * 32 + seg * 8] = cvt8(src);
            *(bf16x8*)&bT[r * 32 + seg * 8] =
                cvt8(&Wih[(size_t)(nt * 128 + r) * KX + k0 + seg * 8]);
        }
        __syncthreads();
        bf16x8 af[4], bfr[4];
        for (int x = 0; x < 4; ++x) {
            af[x]  = *(const bf16x8*)&aT[(wm * 64 + x * 16 + ln) * 32 + quad * 8];
            bfr[x] = *(const bf16x8*)&bT[(wn * 64 + x * 16 + ln) * 32 + quad * 8];
        }
        for (int mi = 0; mi < 4; ++mi)
            for (int ni = 0; ni < 4; ++ni)
                acc[mi][ni] = MFMA(af[mi], bfr[ni], acc[mi][ni]);
        __syncthreads();
    }

    for (int ni = 0; ni < 4; ++ni) {
        int g = nt * 128 + wn * 64 + ni * 16 + ln;
        float bias = bih[g] + bhh[g];
        for (int mi = 0; mi < 4; ++mi) {
            int m = mt * 128 + wm * 64 + mi * 16 + quad * 4;  // m = t*32+b, b%4==0
            int t = m >> 5, b = m & 31;
            f32x4 v = acc[mi][ni];
            v[0] += bias; v[1] += bias; v[2] += bias; v[3] += bias;
            *(f32x4*)&pre[((size_t)t * G4 + g) * BATCH + b] = v;
        }
    }
}

// ---------------------------------------------------------------------------
// Kernel B: recurrence. WGs [0,16): WG w owns h-cols [32w,32w+32) => 128 gate
// rows. Whh staged once into 128 KiB LDS, then hoisted into per-wave VGPR
// fragments (no LDS reads in the t-loop; gst scratch aliases the buffer).
// Fence-free barrier: h stored as packed u64 relaxed-agent atomics (sc1
// write-through => at LLC when vmcnt retires); __syncthreads drains vmcnt in
// every wave before tid0 publishes the flag. Readers poll relaxed flags and
// use normal cacheable loads (Hall addresses are write-once per step, never
// cached before their write; kernel launch boundary invalidates caches
// between bench iterations).
// WGs [16,256): convert Wfc (fp32) -> Wfc16 (bf16) for out_kernel, fully
// overlapped with the recurrence (independent work, no flag interaction —
// no deadlock risk if not co-resident).
// ---------------------------------------------------------------------------
__global__ __launch_bounds__(256, 1) void rnn_kernel(
    const float* __restrict__ pre, const float* __restrict__ Whh,
    __bf16* __restrict__ Hall, unsigned* __restrict__ flags,
    const float* __restrict__ Wfc, __bf16* __restrict__ Wfc16) {
    __shared__ char smem[131072];   // 128 KiB: whh staging, then gst scratch

    if (blockIdx.x >= RNN_WG) {
        // ---- Wfc -> bf16 conversion (grid-stride over 8-elem chunks) ----
        if (Wfc16) {
            const int stride = (gridDim.x - RNN_WG) * 256;
            int idx = (blockIdx.x - RNN_WG) * 256 + threadIdx.x;
            for (int i = idx; i < VV * HH / 8; i += stride)
                *(bf16x8*)&Wfc16[(size_t)i * 8] = cvt8(&Wfc[(size_t)i * 8]);
        }
        return;
    }

    __bf16* whh = (__bf16*)smem;    // [128][512] — dead after fragment hoist
    float*  gst = (float*)smem;     // [128][36]  — aliases whh afterwards

    const int tid = threadIdx.x;
    const int w = blockIdx.x;
    const int lane = tid & 63, wv = tid >> 6;
    const int ln = lane & 15, quad = lane >> 4;

    // stage Whh slice (rows: gate q = r>>5, col-local = r&31 -> global gate
    // q*512 + w*32 + (r&31)), fp32 -> bf16, coalesced
    for (int i = tid; i < 128 * 64; i += 256) {
        int r = i >> 6, k = (i & 63) << 3;
        int g = (r >> 5) * 512 + w * 32 + (r & 31);
        *(bf16x8*)&whh[r * 512 + k] = cvt8(&Whh[(size_t)g * HH + k]);
    }
    __syncthreads();

    // hoist B fragments: wave wv owns gate rows [32wv, 32wv+32)
    bf16x8 bfrag[2][16];
#pragma unroll
    for (int nj = 0; nj < 2; ++nj)
#pragma unroll
        for (int kc = 0; kc < 16; ++kc)
            bfrag[nj][kc] = *(const bf16x8*)
                &whh[(wv * 32 + nj * 16 + ln) * 512 + kc * 32 + quad * 8];
    __syncthreads();   // whh now dead; gst may alias

    const int b_pw = tid & 31;      // pointwise batch
    const int nl = tid >> 5;        // pointwise col group: cols 4nl..4nl+3
    const int b0 = quad * 4;
    const size_t preg0 = (size_t)(wv * 512 + w * 32 + ln);
    float c[4] = {0.f, 0.f, 0.f, 0.f};

    for (int t = 0; t < TT; ++t) {
        // issue pre loads before the poll (independent; hides their latency)
        f32x4 acc[2][2];
#pragma unroll
        for (int mi = 0; mi < 2; ++mi)
#pragma unroll
            for (int nj = 0; nj < 2; ++nj)
                acc[mi][nj] = *(const f32x4*)
                    &pre[((size_t)t * G4 + preg0 + nj * 16) * BATCH + mi * 16 + b0];

        if (t > 0) {
            if (tid < RNN_WG) {
                while (__hip_atomic_load(&flags[(t - 1) * RNN_WG + tid],
                                         __ATOMIC_RELAXED,
                                         __HIP_MEMORY_SCOPE_AGENT) == 0) {}
            }
        }
        __syncthreads();   // join pollers; WAR fence for gst reuse

        if (t > 0) {
            const __bf16* hbase = Hall + (size_t)(t - 1) * BATCH * HH;
            bf16x8 a[2][8];
#pragma unroll
            for (int half = 0; half < 2; ++half) {
#pragma unroll
                for (int mi = 0; mi < 2; ++mi)
#pragma unroll
                    for (int kk = 0; kk < 8; ++kk)
                        a[mi][kk] = *(const bf16x8*)
                            &hbase[(size_t)(mi * 16 + ln) * HH +
                                   (half * 8 + kk) * 32 + quad * 8];
#pragma unroll
                for (int kk = 0; kk < 8; ++kk)
#pragma unroll
                    for (int mi = 0; mi < 2; ++mi)
#pragma unroll
                        for (int nj = 0; nj < 2; ++nj)
                            acc[mi][nj] = MFMA(a[mi][kk],
                                               bfrag[nj][half * 8 + kk],
                                               acc[mi][nj]);
            }
        }
#pragma unroll
        for (int mi = 0; mi < 2; ++mi)
#pragma unroll
            for (int nj = 0; nj < 2; ++nj)
                *(f32x4*)&gst[(wv * 32 + nj * 16 + ln) * 36 + mi * 16 + b0] =
                    acc[mi][nj];
        __syncthreads();

        // pointwise: 4 h-cols per thread, packed u64 agent store (sc1)
        union { unsigned long long u; __bf16 h4[4]; } pk;
#pragma unroll
        for (int j = 0; j < 4; ++j) {
            int cl = nl * 4 + j;
            float gi = gst[(cl)      * 36 + b_pw];
            float gf = gst[(32 + cl) * 36 + b_pw];
            float gg = gst[(64 + cl) * 36 + b_pw];
            float go = gst[(96 + cl) * 36 + b_pw];
            c[j] = sigf(gf) * c[j] + sigf(gi) * tanh_fast(gg);
            pk.h4[j] = (__bf16)(sigf(go) * tanh_fast(c[j]));
        }
        __hip_atomic_store(
            (unsigned long long*)&Hall[((size_t)t * BATCH + b_pw) * HH +
                                       w * 32 + nl * 4],
            pk.u, __ATOMIC_RELAXED, __HIP_MEMORY_SCOPE_AGENT);

        __syncthreads();   // every wave drains vmcnt before barrier => all
                           // sc1 h-stores are at the LLC before the flag
        if (tid == 0 && t < TT - 1)
            __hip_atomic_store(&flags[t * RNN_WG + w], 1u, __ATOMIC_RELAXED,
                               __HIP_MEMORY_SCOPE_AGENT);
    }
}

// ---------------------------------------------------------------------------
// Kernel C: out[b][t][n] = Hall[t*32+b][:] . Wfc[n][:] + bfc[n]   (fp32 out)
// BF16W=1: both operands bf16, staged via global_load_lds width-16 (linear
// LDS dest = wave base + lane*16; per-lane global src). Grid is (mt, nt) so
// the 16 blocks sharing one B-tile are dispatch-adjacent (2 per XCD).
// BF16W=0: legacy path (in-kernel fp32->bf16 cvt of Wfc).
// ---------------------------------------------------------------------------
template <int BF16W>
__global__ __launch_bounds__(256) void out_kernel(
    const __bf16* __restrict__ Hall, const float* __restrict__ Wfc,
    const __bf16* __restrict__ Wfc16, const float* __restrict__ bfc,
    float* __restrict__ out) {
    __shared__ __bf16 aT[128 * 32];
    __shared__ __bf16 bT[128 * 32];

    const int tid = threadIdx.x;
    const int mt = blockIdx.x;   // [0,16)
    const int nt = blockIdx.y;   // [0,235)
    const int lane = tid & 63, wv = tid >> 6;
    const int ln = lane & 15, quad = lane >> 4;
    const int wm = wv & 1, wn = wv >> 1;

    f32x4 acc[4][4] = {};
    const size_t aBase = (size_t)mt * 128 * HH;

    for (int kc = 0; kc < 16; ++kc) {
        const int k0 = kc * 32;
        if (BF16W) {
#pragma unroll
            for (int h = 0; h < 2; ++h) {
                int ch = tid + h * 256;            // chunk index, LDS byte = ch*16
                int r = ch >> 2, seg = ch & 3;
                const __bf16* asrc = &Hall[aBase + (size_t)r * HH + k0 + seg * 8];
                int gr = nt * 128 + r;
                if (gr >= VV) gr = VV - 1;         // clamp (stores guarded)
                const __bf16* bsrc = &Wfc16[(size_t)gr * HH + k0 + seg * 8];
                __builtin_amdgcn_global_load_lds(
                    (gvoid*)asrc,
                    (lvoid*)((char*)aT + wv * 1024 + h * 4096), 16, 0, 0);
                __builtin_amdgcn_global_load_lds(
                    (gvoid*)bsrc,
                    (lvoid*)((char*)bT + wv * 1024 + h * 4096), 16, 0, 0);
            }
        } else {
            for (int i = tid; i < 512; i += 256) {
                int r = i >> 2, seg = i & 3;
                *(bf16x8*)&aT[r * 32 + seg * 8] =
                    *(const bf16x8*)&Hall[aBase + (size_t)r * HH + k0 + seg * 8];
                int gr = nt * 128 + r;
                if (gr >= VV) gr = VV - 1;
                *(bf16x8*)&bT[r * 32 + seg * 8] =
                    cvt8(&Wfc[(size_t)gr * HH + k0 + seg * 8]);
            }
        }
        __syncthreads();
        bf16x8 af[4], bfr[4];
        for (int x = 0; x < 4; ++x) {
            af[x]  = *(const bf16x8*)&aT[(wm * 64 + x * 16 + ln) * 32 + quad * 8];
            bfr[x] = *(const bf16x8*)&bT[(wn * 64 + x * 16 + ln) * 32 + quad * 8];
        }
        for (int mi = 0; mi < 4; ++mi)
            for (int ni = 0; ni < 4; ++ni)
                acc[mi][ni] = MFMA(af[mi], bfr[ni], acc[mi][ni]);
        __syncthreads();
    }

    for (int ni = 0; ni < 4; ++ni) {
        int n = nt * 128 + wn * 64 + ni * 16 + ln;
        if (n >= VV) continue;
        float bias = bfc[n];
        for (int mi = 0; mi < 4; ++mi) {
            int m = mt * 128 + wm * 64 + mi * 16 + quad * 4;  // m = t*32+b
            for (int r = 0; r < 4; ++r) {
                int mm = m + r, t = mm >> 5, b = mm & 31;
                out[((size_t)b * TT + t) * VV + n] = acc[mi][ni][r] + bias;
            }
        }
    }
}

// ---------------------------------------------------------------------------
extern "C" void kernel_launch(void* const* d_in, const int* in_sizes, int n_in,
                              void* d_out, int out_size, void* d_ws, size_t ws_size,
                              hipStream_t stream) {
    const float* enc      = (const float*)d_in[0];
    const int*   captions = (const int*)d_in[1];
    // d_in[2..7]: We, be, Wd, bd, Wf, bf — dead (softmax over length-1 == 1)
    const float* emb      = (const float*)d_in[8];
    const float* Wih      = (const float*)d_in[9];
    const float* Whh      = (const float*)d_in[10];
    const float* bih      = (const float*)d_in[11];
    const float* bhh      = (const float*)d_in[12];
    const float* Wfc      = (const float*)d_in[13];
    const float* bfc      = (const float*)d_in[14];
    float* out = (float*)d_out;

    // pre (16.8 MB fp32) lives INSIDE d_out (245.8 MB fp32) — dead space until
    // out_kernel overwrites it, strictly after rnn_kernel consumed it.
    float* pre = (float*)d_out;

    uint8_t* w = (uint8_t*)d_ws;
    unsigned* flags = (unsigned*)w;                  // 64*16 u32 (16 KiB rsvd)
    __bf16*   Hall  = (__bf16*)(w + 16384);          // [T][B][H] bf16 = 2 MiB
    const size_t WFC16_OFF = 16384 + (size_t)TT * BATCH * HH * 2;  // 2,113,536
    const bool bf16w = ws_size >= WFC16_OFF + (size_t)VV * HH * 2; // +30.72 MB
    __bf16* Wfc16 = bf16w ? (__bf16*)(w + WFC16_OFF) : (__bf16*)nullptr;

    hipMemsetAsync(flags, 0, 16384, stream);         // ws is poisoned each launch

    pre_kernel<<<dim3(16, 16), 256, 0, stream>>>(enc, captions, emb, Wih, bih, bhh, pre);
    rnn_kernel<<<dim3(256), 256, 0, stream>>>(pre, Whh, Hall, flags, Wfc, Wfc16);
    if (bf16w)
        out_kernel<1><<<dim3(16, 235), 256, 0, stream>>>(Hall, Wfc, Wfc16, bfc, out);
    else
        out_kernel<0><<<dim3(16, 235), 256, 0, stream>>>(Hall, Wfc, Wfc16, bfc, out);
}